// Round 12
// baseline (337.209 us; speedup 1.0000x reference)
//
#include <hip/hip_runtime.h>
#include <hip/hip_bf16.h>
#include <math.h>

#define GRIDN 14
#define L 197
#define H 12
#define DK 64
#define D 768
#define B 32
#define BL (B*L)          // 6304
#define TOPK 32
#define NBH (B*H)         // 384
#define NROW (NBH*L)      // 75648
#define QKV_ELEMS ((size_t)NROW*DK)
#define KROWS 127         // staged K/V rows: slot 0 = row 0, slot r = row r+joffs
#define KTS 129           // transposed KV stride (129 = 1 mod 32 -> 2-way banks)

typedef __attribute__((ext_vector_type(8))) short short8;   // 8 bf16
typedef __attribute__((ext_vector_type(4))) float floatx4;

__device__ __forceinline__ void load_lds16(void* lds, const void* g) {
    __builtin_amdgcn_global_load_lds(
        (const __attribute__((address_space(1))) unsigned int*)g,
        (__attribute__((address_space(3))) unsigned int*)lds, 16, 0, 0);
}

// ---------------------------------------------------------------------------
// prep: z<4 -> LDS-tiled transpose+cast of Wq/Wk/Wv/Wo to bf16 [n][k]
//        (Wq,Wk also emit lo-part); z==4 -> cast x to (hi,lo) bf16.
// ---------------------------------------------------------------------------
__global__ __launch_bounds__(256)
void prep(const float* __restrict__ x,
          const float* __restrict__ Wq, const float* __restrict__ Wk,
          const float* __restrict__ Wv, const float* __restrict__ Wo,
          __hip_bfloat16* __restrict__ xh, __hip_bfloat16* __restrict__ xl,
          __hip_bfloat16* __restrict__ WqTh, __hip_bfloat16* __restrict__ WqTl,
          __hip_bfloat16* __restrict__ WkTh, __hip_bfloat16* __restrict__ WkTl,
          __hip_bfloat16* __restrict__ WvT,  __hip_bfloat16* __restrict__ WoT)
{
    const int z = blockIdx.z;
    if (z == 4) {
        int lin = (blockIdx.y * 24 + blockIdx.x) * 256 + threadIdx.x;
        for (int i = lin; i < BL * D / 4; i += 24 * 24 * 256) {
            float4 v = ((const float4*)x)[i];
            union { __hip_bfloat16 b[4]; short4 s; } hh, ll;
            float f[4] = {v.x, v.y, v.z, v.w};
            #pragma unroll
            for (int j = 0; j < 4; ++j) {
                __hip_bfloat16 h = __float2bfloat16(f[j]);
                hh.b[j] = h;
                ll.b[j] = __float2bfloat16(f[j] - __bfloat162float(h));
            }
            ((short4*)xh)[i] = hh.s;
            ((short4*)xl)[i] = ll.s;
        }
        return;
    }
    __shared__ float tile[32][33];
    const float* src = (z == 0) ? Wq : (z == 1) ? Wk : (z == 2) ? Wv : Wo;
    __hip_bfloat16* dh = (z == 0) ? WqTh : (z == 1) ? WkTh : (z == 2) ? WvT : WoT;
    __hip_bfloat16* dl = (z == 0) ? WqTl : (z == 1) ? WkTl : nullptr;
    const int k0 = blockIdx.y * 32, n0 = blockIdx.x * 32;
    const int tx = threadIdx.x & 31, ty = threadIdx.x >> 5;

    for (int r = ty; r < 32; r += 8)
        tile[r][tx] = src[(size_t)(k0 + r) * D + n0 + tx];
    __syncthreads();
    for (int r = ty; r < 32; r += 8) {
        float v = tile[tx][r];
        __hip_bfloat16 h = __float2bfloat16(v);
        dh[(size_t)(n0 + r) * D + k0 + tx] = h;
        if (dl) dl[(size_t)(n0 + r) * D + k0 + tx] =
            __float2bfloat16(v - __bfloat162float(h));
    }
}

// ---------------------------------------------------------------------------
// Fused QKV GEMM: grid (50, 18). blockIdx.y/6 selects Q(3-term) / K(3-term)
// / V(1-term). 128x128 tile, TBK=32, XOR-swizzled LDS.
// (R6-verified. R7 dbuf / R8 XCD-swizzle / R9 tile-halving all regressed:
// this structure is a local optimum w.r.t. those levers. ~606 TF-effective.)
// ---------------------------------------------------------------------------
__global__ __launch_bounds__(256)
void gemm_qkv(const __hip_bfloat16* __restrict__ xh, const __hip_bfloat16* __restrict__ xl,
              const __hip_bfloat16* __restrict__ Wqh, const __hip_bfloat16* __restrict__ Wql,
              const __hip_bfloat16* __restrict__ Wkh, const __hip_bfloat16* __restrict__ Wkl,
              const __hip_bfloat16* __restrict__ Wvh,
              const float* __restrict__ bq, const float* __restrict__ bk,
              const float* __restrict__ bv,
              float* __restrict__ Qb, float* __restrict__ Kb, float* __restrict__ Vb)
{
    __shared__ __attribute__((aligned(16))) __hip_bfloat16 Ash[128 * 32];
    __shared__ __attribute__((aligned(16))) __hip_bfloat16 Bsh[128 * 32];
    __shared__ __attribute__((aligned(16))) __hip_bfloat16 Asl[128 * 32];
    __shared__ __attribute__((aligned(16))) __hip_bfloat16 Bsl[128 * 32];

    const int grp = blockIdx.y / 6, nt = blockIdx.y % 6;
    const __hip_bfloat16 *Bth, *Btl; const float* bias; float* C;
    if (grp == 0)      { Bth = Wqh; Btl = Wql; bias = bq; C = Qb; }
    else if (grp == 1) { Bth = Wkh; Btl = Wkl; bias = bk; C = Kb; }
    else               { Bth = Wvh; Btl = nullptr; bias = bv; C = Vb; }
    const bool split = (grp < 2);

    const int tid = threadIdx.x;
    const int wave = tid >> 6, lane = tid & 63;
    const int quad = lane >> 4, l16 = lane & 15;
    const int m0 = blockIdx.x * 128, n0 = nt * 128;
    const int wm = (wave & 1) * 64, wn = (wave >> 1) * 64;

    floatx4 acc[4][4] = {};

    int s_r[2], s_cs[2];
    #pragma unroll
    for (int u = 0; u < 2; ++u) {
        int idx = tid + u * 256;
        s_r[u] = idx >> 2; s_cs[u] = idx & 3;
    }

    for (int k0 = 0; k0 < D; k0 += 32) {
        #pragma unroll
        for (int u = 0; u < 2; ++u) {
            int r = s_r[u];
            int csrc = s_cs[u] ^ ((r >> 1) & 3);          // XOR swizzle
            int gm = m0 + r; if (gm >= BL) gm = BL - 1;
            size_t aoff = (size_t)gm * D + k0 + csrc * 8;
            size_t boff = (size_t)(n0 + r) * D + k0 + csrc * 8;
            int lds_off = (wave * 64 + u * 256) * 16;
            load_lds16((char*)Ash + lds_off, xh + aoff);
            load_lds16((char*)Bsh + lds_off, Bth + boff);
            if (split) {
                load_lds16((char*)Asl + lds_off, xl + aoff);
                load_lds16((char*)Bsl + lds_off, Btl + boff);
            }
        }
        __syncthreads();

        short8 ah[4], bh[4];
        #pragma unroll
        for (int a = 0; a < 4; ++a) {
            int r = wm + a * 16 + l16;
            int slot = (r << 2) + (quad ^ ((r >> 1) & 3));
            ah[a] = *(const short8*)((const char*)Ash + (slot << 4));
        }
        #pragma unroll
        for (int b2 = 0; b2 < 4; ++b2) {
            int r = wn + b2 * 16 + l16;
            int slot = (r << 2) + (quad ^ ((r >> 1) & 3));
            bh[b2] = *(const short8*)((const char*)Bsh + (slot << 4));
        }
        if (split) {
            short8 al[4], bl[4];
            #pragma unroll
            for (int a = 0; a < 4; ++a) {
                int r = wm + a * 16 + l16;
                int slot = (r << 2) + (quad ^ ((r >> 1) & 3));
                al[a] = *(const short8*)((const char*)Asl + (slot << 4));
            }
            #pragma unroll
            for (int b2 = 0; b2 < 4; ++b2) {
                int r = wn + b2 * 16 + l16;
                int slot = (r << 2) + (quad ^ ((r >> 1) & 3));
                bl[b2] = *(const short8*)((const char*)Bsl + (slot << 4));
            }
            #pragma unroll
            for (int a = 0; a < 4; ++a)
                #pragma unroll
                for (int b2 = 0; b2 < 4; ++b2) {
                    acc[a][b2] = __builtin_amdgcn_mfma_f32_16x16x32_bf16(
                        al[a], bh[b2], acc[a][b2], 0, 0, 0);
                    acc[a][b2] = __builtin_amdgcn_mfma_f32_16x16x32_bf16(
                        ah[a], bl[b2], acc[a][b2], 0, 0, 0);
                }
        }
        #pragma unroll
        for (int a = 0; a < 4; ++a)
            #pragma unroll
            for (int b2 = 0; b2 < 4; ++b2)
                acc[a][b2] = __builtin_amdgcn_mfma_f32_16x16x32_bf16(
                    ah[a], bh[b2], acc[a][b2], 0, 0, 0);
        __syncthreads();
    }

    #pragma unroll
    for (int b2 = 0; b2 < 4; ++b2) {
        int n = n0 + wn + b2 * 16 + l16;
        float bvv = bias[n];
        int hh = n >> 6, dd = n & 63;
        #pragma unroll
        for (int a = 0; a < 4; ++a) {
            #pragma unroll
            for (int r = 0; r < 4; ++r) {
                int m = m0 + wm + a * 16 + quad * 4 + r;
                if (m < BL) {
                    int bb = m / L, ll = m % L;
                    C[((((size_t)bb * H + hh) * L + ll) << 6) + dd] =
                        acc[a][b2][r] + bvv;
                }
            }
        }
    }
}

// ---------------------------------------------------------------------------
// O-projection GEMM, 128x64 tile: grid (50, 12) = 600 blocks, LDS 12 KB.
// (R11-verified: doubled grid vs 128x128 fixed the 1.17-blocks/CU starvation.)
// ---------------------------------------------------------------------------
__global__ __launch_bounds__(256)
void gemm_o(const __hip_bfloat16* __restrict__ A,
            const __hip_bfloat16* __restrict__ Bt,
            const float* __restrict__ bias, float* __restrict__ C)
{
    __shared__ __attribute__((aligned(16))) __hip_bfloat16 As[128 * 32];   // 8 KB
    __shared__ __attribute__((aligned(16))) __hip_bfloat16 Bts[64 * 32];   // 4 KB

    const int tid = threadIdx.x;
    const int wave = tid >> 6, lane = tid & 63;
    const int quad = lane >> 4, l16 = lane & 15;
    const int m0 = blockIdx.x * 128, n0 = blockIdx.y * 64;
    const int wm = (wave & 1) * 64, wn = (wave >> 1) * 32;

    floatx4 acc[4][2] = {};

    int s_r[2], s_cs[2];
    #pragma unroll
    for (int u = 0; u < 2; ++u) {
        int idx2 = tid + u * 256;
        s_r[u] = idx2 >> 2; s_cs[u] = idx2 & 3;
    }
    const int bR = tid >> 2;
    const int bCs = (tid & 3) ^ ((bR >> 1) & 3);

    for (int k0 = 0; k0 < D; k0 += 32) {
        #pragma unroll
        for (int u = 0; u < 2; ++u) {
            int r = s_r[u];
            int csrc = s_cs[u] ^ ((r >> 1) & 3);
            int gm = m0 + r; if (gm >= BL) gm = BL - 1;
            int lds_off = (wave * 64 + u * 256) * 16;
            load_lds16((char*)As + lds_off, A + (size_t)gm * D + k0 + csrc * 8);
        }
        load_lds16((char*)Bts + (wave * 64) * 16,
                   Bt + (size_t)(n0 + bR) * D + k0 + bCs * 8);
        __syncthreads();

        short8 af[4], bf[2];
        #pragma unroll
        for (int a = 0; a < 4; ++a) {
            int r = wm + a * 16 + l16;
            int slot = (r << 2) + (quad ^ ((r >> 1) & 3));
            af[a] = *(const short8*)((const char*)As + (slot << 4));
        }
        #pragma unroll
        for (int b2 = 0; b2 < 2; ++b2) {
            int r = wn + b2 * 16 + l16;
            int slot = (r << 2) + (quad ^ ((r >> 1) & 3));
            bf[b2] = *(const short8*)((const char*)Bts + (slot << 4));
        }
        #pragma unroll
        for (int a = 0; a < 4; ++a)
            #pragma unroll
            for (int b2 = 0; b2 < 2; ++b2)
                acc[a][b2] = __builtin_amdgcn_mfma_f32_16x16x32_bf16(
                    af[a], bf[b2], acc[a][b2], 0, 0, 0);
        __syncthreads();
    }

    #pragma unroll
    for (int b2 = 0; b2 < 2; ++b2) {
        int n = n0 + wn + b2 * 16 + l16;
        float bvv = bias[n];
        #pragma unroll
        for (int a = 0; a < 4; ++a) {
            #pragma unroll
            for (int r = 0; r < 4; ++r) {
                int m = m0 + wm + a * 16 + quad * 4 + r;
                if (m < BL) C[(size_t)m * D + n] = acc[a][b2][r] + bvv;
            }
        }
    }
}

// ---------------------------------------------------------------------------
// attn_patch: grid (NBH, 3), 512 threads.
//  yb=0/1: patch rows 1..196; K/V staged TRANSPOSED: KVT[d][slot], d=0..63,
//          slot=0..126, stride 129 (= 1 mod 32 banks). The old [127][68]
//          row-major tile had row stride = 4 mod 32 -> every float4 read in
//          the dist loop was an 8-way bank conflict (1.98M conflict cycles
//          per dispatch). Transposed + scalar reads: all LDS accesses 2-way
//          (free per m136). LDS 33.0 KB (smaller) -> 3 blocks/CU retained.
//  yb=2:   cls row; early-return branch, KVT-aliased scratch, 8-wave scores.
// ---------------------------------------------------------------------------
__global__ __launch_bounds__(512)
void attn_patch(const float* __restrict__ Q, const float* __restrict__ Kg,
                const float* __restrict__ Vg, const float* __restrict__ logsig,
                float* __restrict__ wout, float* __restrict__ mout,
                __hip_bfloat16* __restrict__ cons)
{
    __shared__ float KVT[64 * KTS];                                  // 33024 B
    __shared__ float qbuf[8][64];                                    //  2048 B
    __shared__ float wjW[99][32];                                    // 12672 B
    __shared__ unsigned char wjJ[99][32];                            //  3168 B
    __shared__ unsigned int winA[L];     // r0 | c0<<8 | Wd<<16 | Hh<<24
    __shared__ unsigned char joff[76];   // [Wd-3][tm] -> (tm/Wd)*14 + tm%Wd

    const int bh = blockIdx.x;
    const int yb = blockIdx.y;
    const int b = bh / H, h = bh % H;
    const int tid = threadIdx.x, wave = tid >> 6, lane = tid & 63;
    const int half = lane & 1;
    const float* Kp = Kg + (size_t)bh * L * DK;
    const float* Vp = Vg + (size_t)bh * L * DK;

    if (yb == 2) {
        // ---------------- cls path (row 0 only) ----------------
        float* clsbuf = KVT;                      // [0..196]
        float* w0 = KVT + 200;                    // [200..231]
        unsigned char* j0 = (unsigned char*)(KVT + 232);
        if (tid < 64) qbuf[0][tid] = Q[(size_t)bh * L * DK + tid];
        __syncthreads();
        const float coefc = -0.5f * expf(-2.0f * logsig[0]);

        {
            int t = wave * 25 + (lane >> 1);
            bool valid = (lane >> 1) < 25 && t < L;
            float s = 0.f;
            if (valid) {
                const float4* kp = (const float4*)&Kp[(size_t)t * DK + (half << 5)];
                const float4* qp = (const float4*)&qbuf[0][half << 5];
                #pragma unroll
                for (int d4 = 0; d4 < 8; ++d4) {
                    float4 qv = qp[d4], kv = kp[d4];
                    float dx = qv.x - kv.x, dy = qv.y - kv.y;
                    float dz = qv.z - kv.z, dw = qv.w - kv.w;
                    s += dx * dx + dy * dy + dz * dz + dw * dw;
                }
            }
            s += __shfl_xor(s, 1);
            if (valid && !half) clsbuf[t] = coefc * s;
        }
        __syncthreads();

        if (wave == 0) {
            const size_t wb = (size_t)(bh * L) * L;
            float orig[4], cur[4]; int selb = 0;
            #pragma unroll
            for (int k = 0; k < 4; ++k) {
                int t = lane + (k << 6);
                float v = (t < L) ? clsbuf[t] : -INFINITY;
                orig[k] = v; cur[k] = v;
            }
            float gmax = -INFINITY;
            for (int it = 0; it < TOPK; ++it) {
                float bv = cur[0]; int bt = lane;
                #pragma unroll
                for (int k = 1; k < 4; ++k)
                    if (cur[k] > bv) { bv = cur[k]; bt = lane + (k << 6); }
                #pragma unroll
                for (int off = 32; off; off >>= 1) {
                    float ov = __shfl_xor(bv, off);
                    int   ot = __shfl_xor(bt, off);
                    if (ov > bv || (ov == bv && ot < bt)) { bv = ov; bt = ot; }
                }
                if (it == 0) gmax = bv;
                if ((bt & 63) == lane) { cur[bt >> 6] = -INFINITY; selb |= 1 << (bt >> 6); }
            }
            float zl = 0.f; float wk[4];
            #pragma unroll
            for (int k = 0; k < 4; ++k) {
                wk[k] = ((selb >> k) & 1) ? __expf(orig[k] - gmax) : 0.f;
                zl += wk[k];
            }
            #pragma unroll
            for (int off = 32; off; off >>= 1) zl += __shfl_xor(zl, off);

            #pragma unroll
            for (int k = 0; k < 4; ++k) {
                int p = lane + (k << 6);
                if (p < L) {
                    float wv = wk[k] / zl;
                    wout[wb + p] = wv;
                    mout[wb + p] = (wv > 1e-6f) ? 1.f : 0.f;
                }
            }
            int slot = 0;
            #pragma unroll
            for (int k = 0; k < 4; ++k) {
                bool sel = (selb >> k) & 1;
                unsigned long long mk = __ballot(sel);
                if (sel) {
                    int tt = slot + (int)__popcll(mk & ((1ull << lane) - 1ull));
                    w0[tt] = wk[k] / zl;
                    j0[tt] = (unsigned char)(lane + (k << 6));
                }
                slot += (int)__popcll(mk);
            }
            float acc = 0.f;
            #pragma unroll
            for (int t2 = 0; t2 < 32; ++t2)
                acc += w0[t2] * Vp[(size_t)j0[t2] * DK + lane];
            cons[((size_t)b * L) * D + h * 64 + lane] = __float2bfloat16(acc);
        }
        return;
    }

    // ---------------- patch path (rows 1..196) ----------
    const int base_i = yb * 99;
    const int joffs = yb ? 70 : 0;       // global K row = slot ? slot+joffs : 0

    if (tid >= 1 && tid < L) {
        int r = (tid - 1) / GRIDN, c = (tid - 1) % GRIDN;
        int r0 = r - 2 < 0 ? 0 : r - 2, r1 = r + 2 > 13 ? 13 : r + 2;
        int c0 = c - 2 < 0 ? 0 : c - 2, c1 = c + 2 > 13 ? 13 : c + 2;
        int Wd = c1 - c0 + 1, Hh = r1 - r0 + 1;
        winA[tid] = (unsigned)r0 | ((unsigned)c0 << 8) |
                    ((unsigned)Wd << 16) | ((unsigned)Hh << 24);
    }
    if (tid < 75) {
        int w = tid / 25 + 3, tm = tid % 25;
        joff[tid] = (unsigned char)((tm / w) * GRIDN + tm % w);
    }

    int pr4[4], pc4[4];
    #pragma unroll
    for (int k = 0; k < 4; ++k) {
        int p = lane + (k << 6);
        if (p >= 1 && p < L) { pr4[k] = (p - 1) / GRIDN; pc4[k] = (p - 1) % GRIDN; }
        else                 { pr4[k] = 255; pc4[k] = 255; }
    }

    // ---- phase 1: K staging, transposed (float4 read -> 4 scalar writes) ----
    for (int idx = tid; idx < KROWS * 16; idx += 512) {
        int r = idx >> 4, c4 = idx & 15;
        int g = r ? r + joffs : 0;
        float4 v = *(const float4*)&Kp[g * 64 + c4 * 4];
        int d0 = c4 * 4;
        KVT[(d0 + 0) * KTS + r] = v.x;     // banks (4c4+e+r)%32: 2-way
        KVT[(d0 + 1) * KTS + r] = v.y;
        KVT[(d0 + 2) * KTS + r] = v.z;
        KVT[(d0 + 3) * KTS + r] = v.w;
    }
    __syncthreads();

    const float coef = -0.5f * expf(-2.0f * logsig[0]);
    const int starts0[9] = {1, 14, 27, 39, 51, 63, 75, 87, 99};
    const int starts1[9] = {99, 112, 124, 136, 148, 161, 173, 185, 197};
    const int i_begin = yb ? starts1[wave] : starts0[wave];
    const int i_end   = yb ? starts1[wave + 1] : starts0[wave + 1];

    float qreg = (i_begin < i_end)
               ? Q[((size_t)bh * L + i_begin) * 64 + lane] : 0.f;

    for (int i = i_begin; i < i_end; ++i) {
        const int rowid = bh * L + i;
        const size_t wb = (size_t)rowid * L;
        const int local = i - base_i;

        qbuf[wave][lane] = qreg;
        if (i + 1 < i_end)
            qreg = Q[((size_t)rowid + 1) * 64 + lane];

        const unsigned wa = winA[i];
        const int r0 = wa & 255, c0 = (wa >> 8) & 255;
        const int Wd2 = (wa >> 16) & 255, Hh = wa >> 24;
        const int n = Hh * Wd2 + 1;
        const int jbase = 1 + r0 * GRIDN + c0;

        int t = lane >> 1;
        bool valid = t < n;
        float s = 0.f; int j = 0;
        if (valid) {
            if (t > 0) j = jbase + joff[(Wd2 - 3) * 25 + (t - 1)];
            int js = j ? j - joffs : 0;           // LDS slot
            // transposed reads: base + dd*KTS, banks (dd+js)%32 = 2-way free
            const float* kc = &KVT[(half << 5) * KTS + js];
            const float* qv = &qbuf[wave][half << 5];
            float s0 = 0.f, s1 = 0.f, s2 = 0.f, s3 = 0.f;
            #pragma unroll
            for (int dd = 0; dd < 32; dd += 4) {
                float d0 = qv[dd + 0] - kc[(dd + 0) * KTS];
                float d1 = qv[dd + 1] - kc[(dd + 1) * KTS];
                float d2 = qv[dd + 2] - kc[(dd + 2) * KTS];
                float d3 = qv[dd + 3] - kc[(dd + 3) * KTS];
                s0 += d0 * d0; s1 += d1 * d1; s2 += d2 * d2; s3 += d3 * d3;
            }
            s = (s0 + s1) + (s2 + s3);
            j = js;                                // store slot in wjJ
        }
        s += __shfl_xor(s, 1);                     // pair-identical scores now
        float sc = valid ? coef * s : -INFINITY;

        // 5-round reductions over even masks (scores pair-identical).
        float mx = sc;
        #pragma unroll
        for (int off = 32; off >= 2; off >>= 1) mx = fmaxf(mx, __shfl_xor(mx, off));
        float e = valid ? __expf(sc - mx) : 0.f;
        float es = e;
        #pragma unroll
        for (int off = 32; off >= 2; off >>= 1) es += __shfl_xor(es, off);
        float wv = e / es;

        if (!half) {
            float wcv = valid ? wv : 0.f;
            wjW[local][t] = wcv;
            wjJ[local][t] = (unsigned char)(valid ? j : 0);   // LDS slot
        }
        #pragma unroll
        for (int k = 0; k < 4; ++k) {
            int p = lane + (k << 6);
            if (p < L) {
                float wd = 0.f;
                if (p == 0) wd = wjW[local][0];
                else {
                    unsigned du = (unsigned)(pr4[k] - r0);
                    unsigned dv = (unsigned)(pc4[k] - c0);
                    if (du < (unsigned)Hh && dv < (unsigned)Wd2)
                        wd = wjW[local][1 + du * Wd2 + dv];
                }
                wout[wb + p] = wd;
                mout[wb + p] = (wd > 1e-6f) ? 1.f : 0.f;
            }
        }
    }
    __syncthreads();

    // ---- phase 2: V staging over KVT (same transposed layout) ----
    for (int idx = tid; idx < KROWS * 16; idx += 512) {
        int r = idx >> 4, c4 = idx & 15;
        int g = r ? r + joffs : 0;
        float4 v = *(const float4*)&Vp[g * 64 + c4 * 4];
        int d0 = c4 * 4;
        KVT[(d0 + 0) * KTS + r] = v.x;
        KVT[(d0 + 1) * KTS + r] = v.y;
        KVT[(d0 + 2) * KTS + r] = v.z;
        KVT[(d0 + 3) * KTS + r] = v.w;
    }
    __syncthreads();

    const int c_begin = yb ? starts1[wave] : starts0[wave];
    const int c_end   = yb ? starts1[wave + 1] : starts0[wave + 1];

    const float* vrow = &KVT[lane * KTS];   // this lane's dim, indexed by slot
    for (int i = c_begin; i < c_end; ++i) {
        const int local = i - base_i;
        float acc = 0.f;
        #pragma unroll
        for (int t = 0; t < 32; ++t) {
            float w = wjW[local][t];          // wave-broadcast LDS read
            int j = wjJ[local][t];            // LDS slot (pre-mapped)
            acc += w * vrow[j];               // banks (lane+j)%32: 2-way free
        }
        cons[((size_t)b * L + i) * D + h * 64 + lane] = __float2bfloat16(acc);
    }
}

// ---------------------------------------------------------------------------
extern "C" void kernel_launch(void* const* d_in, const int* in_sizes, int n_in,
                              void* d_out, int out_size, void* d_ws, size_t ws_size,
                              hipStream_t stream)
{
    const float* x   = (const float*)d_in[0];
    const float* Wq  = (const float*)d_in[1];
    const float* bq  = (const float*)d_in[2];
    const float* Wk  = (const float*)d_in[3];
    const float* bk  = (const float*)d_in[4];
    const float* Wv  = (const float*)d_in[5];
    const float* bv  = (const float*)d_in[6];
    const float* Wo  = (const float*)d_in[7];
    const float* bo  = (const float*)d_in[8];
    const float* lsg = (const float*)d_in[9];

    float* out  = (float*)d_out;                       // B*L*D
    float* wout = out + QKV_ELEMS;                     // B*H*L*L
    float* mout = wout + (size_t)B * H * L * L;        // B*H*L*L

    float* Qb  = (float*)d_ws;
    float* Kb  = Qb + QKV_ELEMS;
    float* Vb  = Kb + QKV_ELEMS;
    __hip_bfloat16* xh = (__hip_bfloat16*)(Vb + QKV_ELEMS);
    __hip_bfloat16* xl = xh + (size_t)BL * D;
    __hip_bfloat16* WqTh = xl + (size_t)BL * D;
    __hip_bfloat16* WqTl = WqTh + (size_t)D * D;
    __hip_bfloat16* WkTh = WqTl + (size_t)D * D;
    __hip_bfloat16* WkTl = WkTh + (size_t)D * D;
    __hip_bfloat16* WvT  = WkTl + (size_t)D * D;
    __hip_bfloat16* WoT  = WvT  + (size_t)D * D;
    __hip_bfloat16* consb = xh;   // alias: xh dead after gemm_qkv

    prep<<<dim3(24, 24, 5), 256, 0, stream>>>(
        x, Wq, Wk, Wv, Wo, xh, xl, WqTh, WqTl, WkTh, WkTl, WvT, WoT);

    gemm_qkv<<<dim3(50, 18), 256, 0, stream>>>(
        xh, xl, WqTh, WqTl, WkTh, WkTl, WvT, bq, bk, bv, Qb, Kb, Vb);

    attn_patch<<<dim3(NBH, 3), 512, 0, stream>>>(
        Qb, Kb, Vb, lsg, wout, mout, consb);

    gemm_o<<<dim3(50, 12), 256, 0, stream>>>(consb, WoT, bo, out);
}

// Round 13
// 318.542 us; speedup vs baseline: 1.0586x; 1.0586x over previous
//
#include <hip/hip_runtime.h>
#include <hip/hip_bf16.h>
#include <math.h>

#define GRIDN 14
#define L 197
#define H 12
#define DK 64
#define D 768
#define B 32
#define BL (B*L)          // 6304
#define TOPK 32
#define NBH (B*H)         // 384
#define NROW (NBH*L)      // 75648
#define QKV_ELEMS ((size_t)NROW*DK)
#define KSTR 68           // KV row stride in floats (float4-aligned, 17 f4)
#define KROWS 127         // staged K/V rows: slot 0 = row 0, slot r = row r+joffs

typedef __attribute__((ext_vector_type(8))) short short8;   // 8 bf16
typedef __attribute__((ext_vector_type(4))) float floatx4;

__device__ __forceinline__ void load_lds16(void* lds, const void* g) {
    __builtin_amdgcn_global_load_lds(
        (const __attribute__((address_space(1))) unsigned int*)g,
        (__attribute__((address_space(3))) unsigned int*)lds, 16, 0, 0);
}

// ---------------------------------------------------------------------------
// prep: z<4 -> LDS-tiled transpose+cast of Wq/Wk/Wv/Wo to bf16 [n][k]
//        (Wq,Wk also emit lo-part); z==4 -> cast x to (hi,lo) bf16.
// ---------------------------------------------------------------------------
__global__ __launch_bounds__(256)
void prep(const float* __restrict__ x,
          const float* __restrict__ Wq, const float* __restrict__ Wk,
          const float* __restrict__ Wv, const float* __restrict__ Wo,
          __hip_bfloat16* __restrict__ xh, __hip_bfloat16* __restrict__ xl,
          __hip_bfloat16* __restrict__ WqTh, __hip_bfloat16* __restrict__ WqTl,
          __hip_bfloat16* __restrict__ WkTh, __hip_bfloat16* __restrict__ WkTl,
          __hip_bfloat16* __restrict__ WvT,  __hip_bfloat16* __restrict__ WoT)
{
    const int z = blockIdx.z;
    if (z == 4) {
        int lin = (blockIdx.y * 24 + blockIdx.x) * 256 + threadIdx.x;
        for (int i = lin; i < BL * D / 4; i += 24 * 24 * 256) {
            float4 v = ((const float4*)x)[i];
            union { __hip_bfloat16 b[4]; short4 s; } hh, ll;
            float f[4] = {v.x, v.y, v.z, v.w};
            #pragma unroll
            for (int j = 0; j < 4; ++j) {
                __hip_bfloat16 h = __float2bfloat16(f[j]);
                hh.b[j] = h;
                ll.b[j] = __float2bfloat16(f[j] - __bfloat162float(h));
            }
            ((short4*)xh)[i] = hh.s;
            ((short4*)xl)[i] = ll.s;
        }
        return;
    }
    __shared__ float tile[32][33];
    const float* src = (z == 0) ? Wq : (z == 1) ? Wk : (z == 2) ? Wv : Wo;
    __hip_bfloat16* dh = (z == 0) ? WqTh : (z == 1) ? WkTh : (z == 2) ? WvT : WoT;
    __hip_bfloat16* dl = (z == 0) ? WqTl : (z == 1) ? WkTl : nullptr;
    const int k0 = blockIdx.y * 32, n0 = blockIdx.x * 32;
    const int tx = threadIdx.x & 31, ty = threadIdx.x >> 5;

    for (int r = ty; r < 32; r += 8)
        tile[r][tx] = src[(size_t)(k0 + r) * D + n0 + tx];
    __syncthreads();
    for (int r = ty; r < 32; r += 8) {
        float v = tile[tx][r];
        __hip_bfloat16 h = __float2bfloat16(v);
        dh[(size_t)(n0 + r) * D + k0 + tx] = h;
        if (dl) dl[(size_t)(n0 + r) * D + k0 + tx] =
            __float2bfloat16(v - __bfloat162float(h));
    }
}

// ---------------------------------------------------------------------------
// Fused QKV GEMM: grid (50, 18). blockIdx.y/6 selects Q(3-term) / K(3-term)
// / V(1-term). 128x128 tile, TBK=32, XOR-swizzled LDS.
// (R6-verified. R7 dbuf / R8 XCD-swizzle / R9 tile-halving all regressed:
// this structure is a local optimum w.r.t. those levers. ~606 TF-effective.)
// ---------------------------------------------------------------------------
__global__ __launch_bounds__(256)
void gemm_qkv(const __hip_bfloat16* __restrict__ xh, const __hip_bfloat16* __restrict__ xl,
              const __hip_bfloat16* __restrict__ Wqh, const __hip_bfloat16* __restrict__ Wql,
              const __hip_bfloat16* __restrict__ Wkh, const __hip_bfloat16* __restrict__ Wkl,
              const __hip_bfloat16* __restrict__ Wvh,
              const float* __restrict__ bq, const float* __restrict__ bk,
              const float* __restrict__ bv,
              float* __restrict__ Qb, float* __restrict__ Kb, float* __restrict__ Vb)
{
    __shared__ __attribute__((aligned(16))) __hip_bfloat16 Ash[128 * 32];
    __shared__ __attribute__((aligned(16))) __hip_bfloat16 Bsh[128 * 32];
    __shared__ __attribute__((aligned(16))) __hip_bfloat16 Asl[128 * 32];
    __shared__ __attribute__((aligned(16))) __hip_bfloat16 Bsl[128 * 32];

    const int grp = blockIdx.y / 6, nt = blockIdx.y % 6;
    const __hip_bfloat16 *Bth, *Btl; const float* bias; float* C;
    if (grp == 0)      { Bth = Wqh; Btl = Wql; bias = bq; C = Qb; }
    else if (grp == 1) { Bth = Wkh; Btl = Wkl; bias = bk; C = Kb; }
    else               { Bth = Wvh; Btl = nullptr; bias = bv; C = Vb; }
    const bool split = (grp < 2);

    const int tid = threadIdx.x;
    const int wave = tid >> 6, lane = tid & 63;
    const int quad = lane >> 4, l16 = lane & 15;
    const int m0 = blockIdx.x * 128, n0 = nt * 128;
    const int wm = (wave & 1) * 64, wn = (wave >> 1) * 64;

    floatx4 acc[4][4] = {};

    int s_r[2], s_cs[2];
    #pragma unroll
    for (int u = 0; u < 2; ++u) {
        int idx = tid + u * 256;
        s_r[u] = idx >> 2; s_cs[u] = idx & 3;
    }

    for (int k0 = 0; k0 < D; k0 += 32) {
        #pragma unroll
        for (int u = 0; u < 2; ++u) {
            int r = s_r[u];
            int csrc = s_cs[u] ^ ((r >> 1) & 3);          // XOR swizzle
            int gm = m0 + r; if (gm >= BL) gm = BL - 1;
            size_t aoff = (size_t)gm * D + k0 + csrc * 8;
            size_t boff = (size_t)(n0 + r) * D + k0 + csrc * 8;
            int lds_off = (wave * 64 + u * 256) * 16;
            load_lds16((char*)Ash + lds_off, xh + aoff);
            load_lds16((char*)Bsh + lds_off, Bth + boff);
            if (split) {
                load_lds16((char*)Asl + lds_off, xl + aoff);
                load_lds16((char*)Bsl + lds_off, Btl + boff);
            }
        }
        __syncthreads();

        short8 ah[4], bh[4];
        #pragma unroll
        for (int a = 0; a < 4; ++a) {
            int r = wm + a * 16 + l16;
            int slot = (r << 2) + (quad ^ ((r >> 1) & 3));
            ah[a] = *(const short8*)((const char*)Ash + (slot << 4));
        }
        #pragma unroll
        for (int b2 = 0; b2 < 4; ++b2) {
            int r = wn + b2 * 16 + l16;
            int slot = (r << 2) + (quad ^ ((r >> 1) & 3));
            bh[b2] = *(const short8*)((const char*)Bsh + (slot << 4));
        }
        if (split) {
            short8 al[4], bl[4];
            #pragma unroll
            for (int a = 0; a < 4; ++a) {
                int r = wm + a * 16 + l16;
                int slot = (r << 2) + (quad ^ ((r >> 1) & 3));
                al[a] = *(const short8*)((const char*)Asl + (slot << 4));
            }
            #pragma unroll
            for (int b2 = 0; b2 < 4; ++b2) {
                int r = wn + b2 * 16 + l16;
                int slot = (r << 2) + (quad ^ ((r >> 1) & 3));
                bl[b2] = *(const short8*)((const char*)Bsl + (slot << 4));
            }
            #pragma unroll
            for (int a = 0; a < 4; ++a)
                #pragma unroll
                for (int b2 = 0; b2 < 4; ++b2) {
                    acc[a][b2] = __builtin_amdgcn_mfma_f32_16x16x32_bf16(
                        al[a], bh[b2], acc[a][b2], 0, 0, 0);
                    acc[a][b2] = __builtin_amdgcn_mfma_f32_16x16x32_bf16(
                        ah[a], bl[b2], acc[a][b2], 0, 0, 0);
                }
        }
        #pragma unroll
        for (int a = 0; a < 4; ++a)
            #pragma unroll
            for (int b2 = 0; b2 < 4; ++b2)
                acc[a][b2] = __builtin_amdgcn_mfma_f32_16x16x32_bf16(
                    ah[a], bh[b2], acc[a][b2], 0, 0, 0);
        __syncthreads();
    }

    #pragma unroll
    for (int b2 = 0; b2 < 4; ++b2) {
        int n = n0 + wn + b2 * 16 + l16;
        float bvv = bias[n];
        int hh = n >> 6, dd = n & 63;
        #pragma unroll
        for (int a = 0; a < 4; ++a) {
            #pragma unroll
            for (int r = 0; r < 4; ++r) {
                int m = m0 + wm + a * 16 + quad * 4 + r;
                if (m < BL) {
                    int bb = m / L, ll = m % L;
                    C[((((size_t)bb * H + hh) * L + ll) << 6) + dd] =
                        acc[a][b2][r] + bvv;
                }
            }
        }
    }
}

// ---------------------------------------------------------------------------
// O-projection GEMM, 128x64 tile: grid (50, 12) = 600 blocks, LDS 12 KB.
// (R11-verified: doubled grid vs 128x128 fixed the 1.17-blocks/CU starvation.)
// ---------------------------------------------------------------------------
__global__ __launch_bounds__(256)
void gemm_o(const __hip_bfloat16* __restrict__ A,
            const __hip_bfloat16* __restrict__ Bt,
            const float* __restrict__ bias, float* __restrict__ C)
{
    __shared__ __attribute__((aligned(16))) __hip_bfloat16 As[128 * 32];   // 8 KB
    __shared__ __attribute__((aligned(16))) __hip_bfloat16 Bts[64 * 32];   // 4 KB

    const int tid = threadIdx.x;
    const int wave = tid >> 6, lane = tid & 63;
    const int quad = lane >> 4, l16 = lane & 15;
    const int m0 = blockIdx.x * 128, n0 = blockIdx.y * 64;
    const int wm = (wave & 1) * 64, wn = (wave >> 1) * 32;

    floatx4 acc[4][2] = {};

    int s_r[2], s_cs[2];
    #pragma unroll
    for (int u = 0; u < 2; ++u) {
        int idx2 = tid + u * 256;
        s_r[u] = idx2 >> 2; s_cs[u] = idx2 & 3;
    }
    const int bR = tid >> 2;
    const int bCs = (tid & 3) ^ ((bR >> 1) & 3);

    for (int k0 = 0; k0 < D; k0 += 32) {
        #pragma unroll
        for (int u = 0; u < 2; ++u) {
            int r = s_r[u];
            int csrc = s_cs[u] ^ ((r >> 1) & 3);
            int gm = m0 + r; if (gm >= BL) gm = BL - 1;
            int lds_off = (wave * 64 + u * 256) * 16;
            load_lds16((char*)As + lds_off, A + (size_t)gm * D + k0 + csrc * 8);
        }
        load_lds16((char*)Bts + (wave * 64) * 16,
                   Bt + (size_t)(n0 + bR) * D + k0 + bCs * 8);
        __syncthreads();

        short8 af[4], bf[2];
        #pragma unroll
        for (int a = 0; a < 4; ++a) {
            int r = wm + a * 16 + l16;
            int slot = (r << 2) + (quad ^ ((r >> 1) & 3));
            af[a] = *(const short8*)((const char*)As + (slot << 4));
        }
        #pragma unroll
        for (int b2 = 0; b2 < 2; ++b2) {
            int r = wn + b2 * 16 + l16;
            int slot = (r << 2) + (quad ^ ((r >> 1) & 3));
            bf[b2] = *(const short8*)((const char*)Bts + (slot << 4));
        }
        #pragma unroll
        for (int a = 0; a < 4; ++a)
            #pragma unroll
            for (int b2 = 0; b2 < 2; ++b2)
                acc[a][b2] = __builtin_amdgcn_mfma_f32_16x16x32_bf16(
                    af[a], bf[b2], acc[a][b2], 0, 0, 0);
        __syncthreads();
    }

    #pragma unroll
    for (int b2 = 0; b2 < 2; ++b2) {
        int n = n0 + wn + b2 * 16 + l16;
        float bvv = bias[n];
        #pragma unroll
        for (int a = 0; a < 4; ++a) {
            #pragma unroll
            for (int r = 0; r < 4; ++r) {
                int m = m0 + wm + a * 16 + quad * 4 + r;
                if (m < BL) C[(size_t)m * D + n] = acc[a][b2][r] + bvv;
            }
        }
    }
}

// ---------------------------------------------------------------------------
// attn_patch: grid (NBH, 3), 512 threads.  (R10/R11-verified layout.)
//  yb=0/1: patch rows 1..196; KV[127][68] float4 reads. NOTE: the apparent
//          8-way bank conflict here is ~1.9k cycles/SIMD/dispatch = noise
//          (R12's transpose "fix" made it 6.5x worse via scalar-read blowup
//          + js clustering mod 32 — do not retry; normalize
//          SQ_LDS_BANK_CONFLICT by SIMD count before targeting it).
//  yb=2:   cls row; early-return branch, KV-aliased scratch, 8-wave scores.
//  __expf + 5-round pair-identical softmax reductions (R10-verified).
// ---------------------------------------------------------------------------
__global__ __launch_bounds__(512)
void attn_patch(const float* __restrict__ Q, const float* __restrict__ Kg,
                const float* __restrict__ Vg, const float* __restrict__ logsig,
                float* __restrict__ wout, float* __restrict__ mout,
                __hip_bfloat16* __restrict__ cons)
{
    __shared__ __attribute__((aligned(16))) float KV[KROWS * KSTR];  // 34544 B
    __shared__ float qbuf[8][64];                                    //  2048 B
    __shared__ float wjW[99][32];                                    // 12672 B
    __shared__ unsigned char wjJ[99][32];                            //  3168 B
    __shared__ unsigned int winA[L];     // r0 | c0<<8 | Wd<<16 | Hh<<24
    __shared__ unsigned char joff[76];   // [Wd-3][tm] -> (tm/Wd)*14 + tm%Wd

    const int bh = blockIdx.x;
    const int yb = blockIdx.y;
    const int b = bh / H, h = bh % H;
    const int tid = threadIdx.x, wave = tid >> 6, lane = tid & 63;
    const int half = lane & 1;
    const float* Kp = Kg + (size_t)bh * L * DK;
    const float* Vp = Vg + (size_t)bh * L * DK;

    if (yb == 2) {
        // ---------------- cls path (row 0 only) ----------------
        float* clsbuf = KV;                       // [0..196]
        float* w0 = KV + 200;                     // [200..231]
        unsigned char* j0 = (unsigned char*)(KV + 232);
        if (tid < 64) qbuf[0][tid] = Q[(size_t)bh * L * DK + tid];
        __syncthreads();
        const float coefc = -0.5f * expf(-2.0f * logsig[0]);

        {
            int t = wave * 25 + (lane >> 1);
            bool valid = (lane >> 1) < 25 && t < L;
            float s = 0.f;
            if (valid) {
                const float4* kp = (const float4*)&Kp[(size_t)t * DK + (half << 5)];
                const float4* qp = (const float4*)&qbuf[0][half << 5];
                #pragma unroll
                for (int d4 = 0; d4 < 8; ++d4) {
                    float4 qv = qp[d4], kv = kp[d4];
                    float dx = qv.x - kv.x, dy = qv.y - kv.y;
                    float dz = qv.z - kv.z, dw = qv.w - kv.w;
                    s += dx * dx + dy * dy + dz * dz + dw * dw;
                }
            }
            s += __shfl_xor(s, 1);
            if (valid && !half) clsbuf[t] = coefc * s;
        }
        __syncthreads();

        if (wave == 0) {
            const size_t wb = (size_t)(bh * L) * L;
            float orig[4], cur[4]; int selb = 0;
            #pragma unroll
            for (int k = 0; k < 4; ++k) {
                int t = lane + (k << 6);
                float v = (t < L) ? clsbuf[t] : -INFINITY;
                orig[k] = v; cur[k] = v;
            }
            float gmax = -INFINITY;
            for (int it = 0; it < TOPK; ++it) {
                float bv = cur[0]; int bt = lane;
                #pragma unroll
                for (int k = 1; k < 4; ++k)
                    if (cur[k] > bv) { bv = cur[k]; bt = lane + (k << 6); }
                #pragma unroll
                for (int off = 32; off; off >>= 1) {
                    float ov = __shfl_xor(bv, off);
                    int   ot = __shfl_xor(bt, off);
                    if (ov > bv || (ov == bv && ot < bt)) { bv = ov; bt = ot; }
                }
                if (it == 0) gmax = bv;
                if ((bt & 63) == lane) { cur[bt >> 6] = -INFINITY; selb |= 1 << (bt >> 6); }
            }
            float zl = 0.f; float wk[4];
            #pragma unroll
            for (int k = 0; k < 4; ++k) {
                wk[k] = ((selb >> k) & 1) ? __expf(orig[k] - gmax) : 0.f;
                zl += wk[k];
            }
            #pragma unroll
            for (int off = 32; off; off >>= 1) zl += __shfl_xor(zl, off);

            #pragma unroll
            for (int k = 0; k < 4; ++k) {
                int p = lane + (k << 6);
                if (p < L) {
                    float wv = wk[k] / zl;
                    wout[wb + p] = wv;
                    mout[wb + p] = (wv > 1e-6f) ? 1.f : 0.f;
                }
            }
            int slot = 0;
            #pragma unroll
            for (int k = 0; k < 4; ++k) {
                bool sel = (selb >> k) & 1;
                unsigned long long mk = __ballot(sel);
                if (sel) {
                    int tt = slot + (int)__popcll(mk & ((1ull << lane) - 1ull));
                    w0[tt] = wk[k] / zl;
                    j0[tt] = (unsigned char)(lane + (k << 6));
                }
                slot += (int)__popcll(mk);
            }
            float acc = 0.f;
            #pragma unroll
            for (int t2 = 0; t2 < 32; ++t2)
                acc += w0[t2] * Vp[(size_t)j0[t2] * DK + lane];
            cons[((size_t)b * L) * D + h * 64 + lane] = __float2bfloat16(acc);
        }
        return;
    }

    // ---------------- patch path (rows 1..196) ----------
    const int base_i = yb * 99;
    const int joffs = yb ? 70 : 0;       // global K row = slot ? slot+joffs : 0

    if (tid >= 1 && tid < L) {
        int r = (tid - 1) / GRIDN, c = (tid - 1) % GRIDN;
        int r0 = r - 2 < 0 ? 0 : r - 2, r1 = r + 2 > 13 ? 13 : r + 2;
        int c0 = c - 2 < 0 ? 0 : c - 2, c1 = c + 2 > 13 ? 13 : c + 2;
        int Wd = c1 - c0 + 1, Hh = r1 - r0 + 1;
        winA[tid] = (unsigned)r0 | ((unsigned)c0 << 8) |
                    ((unsigned)Wd << 16) | ((unsigned)Hh << 24);
    }
    if (tid < 75) {
        int w = tid / 25 + 3, tm = tid % 25;
        joff[tid] = (unsigned char)((tm / w) * GRIDN + tm % w);
    }

    int pr4[4], pc4[4];
    #pragma unroll
    for (int k = 0; k < 4; ++k) {
        int p = lane + (k << 6);
        if (p >= 1 && p < L) { pr4[k] = (p - 1) / GRIDN; pc4[k] = (p - 1) % GRIDN; }
        else                 { pr4[k] = 255; pc4[k] = 255; }
    }

    for (int idx = tid; idx < KROWS * 16; idx += 512) {
        int r = idx >> 4, c4 = idx & 15;
        int g = r ? r + joffs : 0;
        *(float4*)&KV[r * KSTR + c4 * 4] = *(const float4*)&Kp[g * 64 + c4 * 4];
    }
    __syncthreads();

    const float coef = -0.5f * expf(-2.0f * logsig[0]);
    const int starts0[9] = {1, 14, 27, 39, 51, 63, 75, 87, 99};
    const int starts1[9] = {99, 112, 124, 136, 148, 161, 173, 185, 197};
    const int i_begin = yb ? starts1[wave] : starts0[wave];
    const int i_end   = yb ? starts1[wave + 1] : starts0[wave + 1];

    float qreg = (i_begin < i_end)
               ? Q[((size_t)bh * L + i_begin) * 64 + lane] : 0.f;

    for (int i = i_begin; i < i_end; ++i) {
        const int rowid = bh * L + i;
        const size_t wb = (size_t)rowid * L;
        const int local = i - base_i;

        qbuf[wave][lane] = qreg;
        if (i + 1 < i_end)
            qreg = Q[((size_t)rowid + 1) * 64 + lane];

        const unsigned wa = winA[i];
        const int r0 = wa & 255, c0 = (wa >> 8) & 255;
        const int Wd2 = (wa >> 16) & 255, Hh = wa >> 24;
        const int n = Hh * Wd2 + 1;
        const int jbase = 1 + r0 * GRIDN + c0;

        int t = lane >> 1;
        bool valid = t < n;
        float s = 0.f; int j = 0;
        if (valid) {
            if (t > 0) j = jbase + joff[(Wd2 - 3) * 25 + (t - 1)];
            int js = j ? j - joffs : 0;           // LDS slot
            const float4* kp = (const float4*)&KV[js * KSTR + (half << 5)];
            const float4* qp = (const float4*)&qbuf[wave][half << 5];
            #pragma unroll
            for (int d4 = 0; d4 < 8; ++d4) {
                float4 qv = qp[d4], kv = kp[d4];
                float dx = qv.x - kv.x, dy = qv.y - kv.y;
                float dz = qv.z - kv.z, dw = qv.w - kv.w;
                s += dx * dx + dy * dy + dz * dz + dw * dw;
            }
            j = js;                                // store slot in wjJ
        }
        s += __shfl_xor(s, 1);                     // pair-identical scores now
        float sc = valid ? coef * s : -INFINITY;

        // 5-round reductions over even masks (scores pair-identical).
        float mx = sc;
        #pragma unroll
        for (int off = 32; off >= 2; off >>= 1) mx = fmaxf(mx, __shfl_xor(mx, off));
        float e = valid ? __expf(sc - mx) : 0.f;
        float es = e;
        #pragma unroll
        for (int off = 32; off >= 2; off >>= 1) es += __shfl_xor(es, off);
        float wv = e / es;

        if (!half) {
            float wcv = valid ? wv : 0.f;
            wjW[local][t] = wcv;
            wjJ[local][t] = (unsigned char)(valid ? j : 0);   // LDS slot
        }
        #pragma unroll
        for (int k = 0; k < 4; ++k) {
            int p = lane + (k << 6);
            if (p < L) {
                float wd = 0.f;
                if (p == 0) wd = wjW[local][0];
                else {
                    unsigned du = (unsigned)(pr4[k] - r0);
                    unsigned dv = (unsigned)(pc4[k] - c0);
                    if (du < (unsigned)Hh && dv < (unsigned)Wd2)
                        wd = wjW[local][1 + du * Wd2 + dv];
                }
                wout[wb + p] = wd;
                mout[wb + p] = (wd > 1e-6f) ? 1.f : 0.f;
            }
        }
    }
    __syncthreads();

    // ---- phase 2: V staging over KV (same 127-row window) ----
    for (int idx = tid; idx < KROWS * 16; idx += 512) {
        int r = idx >> 4, c4 = idx & 15;
        int g = r ? r + joffs : 0;
        *(float4*)&KV[r * KSTR + c4 * 4] = *(const float4*)&Vp[g * 64 + c4 * 4];
    }
    __syncthreads();

    const int c_begin = yb ? starts1[wave] : starts0[wave];
    const int c_end   = yb ? starts1[wave + 1] : starts0[wave + 1];

    for (int i = c_begin; i < c_end; ++i) {
        const int local = i - base_i;
        float acc = 0.f;
        #pragma unroll
        for (int t = 0; t < 32; ++t) {
            float w = wjW[local][t];          // wave-broadcast LDS read
            int j = wjJ[local][t];            // LDS slot (pre-mapped)
            acc += w * KV[j * KSTR + lane];   // 2-way bank alias = free
        }
        cons[((size_t)b * L + i) * D + h * 64 + lane] = __float2bfloat16(acc);
    }
}

// ---------------------------------------------------------------------------
extern "C" void kernel_launch(void* const* d_in, const int* in_sizes, int n_in,
                              void* d_out, int out_size, void* d_ws, size_t ws_size,
                              hipStream_t stream)
{
    const float* x   = (const float*)d_in[0];
    const float* Wq  = (const float*)d_in[1];
    const float* bq  = (const float*)d_in[2];
    const float* Wk  = (const float*)d_in[3];
    const float* bk  = (const float*)d_in[4];
    const float* Wv  = (const float*)d_in[5];
    const float* bv  = (const float*)d_in[6];
    const float* Wo  = (const float*)d_in[7];
    const float* bo  = (const float*)d_in[8];
    const float* lsg = (const float*)d_in[9];

    float* out  = (float*)d_out;                       // B*L*D
    float* wout = out + QKV_ELEMS;                     // B*H*L*L
    float* mout = wout + (size_t)B * H * L * L;        // B*H*L*L

    float* Qb  = (float*)d_ws;
    float* Kb  = Qb + QKV_ELEMS;
    float* Vb  = Kb + QKV_ELEMS;
    __hip_bfloat16* xh = (__hip_bfloat16*)(Vb + QKV_ELEMS);
    __hip_bfloat16* xl = xh + (size_t)BL * D;
    __hip_bfloat16* WqTh = xl + (size_t)BL * D;
    __hip_bfloat16* WqTl = WqTh + (size_t)D * D;
    __hip_bfloat16* WkTh = WqTl + (size_t)D * D;
    __hip_bfloat16* WkTl = WkTh + (size_t)D * D;
    __hip_bfloat16* WvT  = WkTl + (size_t)D * D;
    __hip_bfloat16* WoT  = WvT  + (size_t)D * D;
    __hip_bfloat16* consb = xh;   // alias: xh dead after gemm_qkv

    prep<<<dim3(24, 24, 5), 256, 0, stream>>>(
        x, Wq, Wk, Wv, Wo, xh, xl, WqTh, WqTl, WkTh, WkTl, WvT, WoT);

    gemm_qkv<<<dim3(50, 18), 256, 0, stream>>>(
        xh, xl, WqTh, WqTl, WkTh, WkTl, WvT, bq, bk, bv, Qb, Kb, Vb);

    attn_patch<<<dim3(NBH, 3), 512, 0, stream>>>(
        Qb, Kb, Vb, lsg, wout, mout, consb);

    gemm_o<<<dim3(50, 12), 256, 0, stream>>>(consb, WoT, bo, out);
}